// Round 16
// baseline (2001.195 us; speedup 1.0000x reference)
//
#include <hip/hip_runtime.h>
#include <stdint.h>
#include <stddef.h>

#define BATCH 128
#define NFRAMES 256
#define EMBED 768
#define RES 2048
#define NCLS 1000
#define NWG 128

typedef __attribute__((ext_vector_type(8))) short bf16x8;
typedef __attribute__((ext_vector_type(4))) float f32x4;
typedef unsigned short u16;

__device__ inline u16 f2bf(float f) {
    union { float f; unsigned u; } v; v.f = f;
    unsigned r = v.u + 0x7FFFu + ((v.u >> 16) & 1u);
    return (u16)(r >> 16);
}
__device__ inline float bf2f(u16 h) {
    union { unsigned u; float f; } v; v.u = ((unsigned)h) << 16;
    return v.f;
}
// tanh(x) = 1 - 2/(e^{2x}+1), via HW exp2 + rcp (saturates correctly)
__device__ inline float tanh_fast(float x) {
    float z = __builtin_amdgcn_exp2f(x * 2.885390081777927f);  // e^{2x}
    return 1.f - 2.f * __builtin_amdgcn_rcpf(z + 1.f);
}
// 64-lane poll over a group's 32 stamp flags (2 lanes/flag), uncached
__device__ inline void poll32(const unsigned* pf, unsigned stamp) {
    unsigned f;
    do {
        asm volatile("global_load_dword %0, %1, off sc0 sc1\n\ts_waitcnt vmcnt(0)"
                     : "=v"(f) : "v"(pf) : "memory");
        if (__all((int)(f >= stamp))) break;
        __builtin_amdgcn_s_sleep(2);
    } while (1);
}

// ---------------- fp32 -> bf16 convert, vectorized x4 ----------------
__global__ __launch_bounds__(256) void cvt_kernel(const float* __restrict__ in,
                                                  u16* __restrict__ out, int n4) {
    int i = blockIdx.x * blockDim.x + threadIdx.x;
    int stride = gridDim.x * blockDim.x;
    for (; i < n4; i += stride) {
        float4 v = ((const float4*)in)[i];
        ushort4 o;
        o.x = f2bf(v.x); o.y = f2bf(v.y); o.z = f2bf(v.z); o.w = f2bf(v.w);
        ((ushort4*)out)[i] = o;
    }
}

// ---------------- projection: u[t,b,r] = sum_e x[b,t,e] * W_in[r,e] ----------------
__global__ __launch_bounds__(256) void proj_kernel(const u16* __restrict__ xb,
                                                   const u16* __restrict__ win,
                                                   u16* __restrict__ u) {
    int lane = threadIdx.x & 63;
    int w = threadIdx.x >> 6;
    int wm = w >> 1, wn = w & 1;
    int m0 = blockIdx.x * 128 + wm * 64;
    int n0 = blockIdx.y * 128 + wn * 64;
    int lr = lane & 15;
    int lk = (lane >> 4) * 8;

    f32x4 acc[4][4];
#pragma unroll
    for (int i = 0; i < 4; i++)
#pragma unroll
        for (int j = 0; j < 4; j++) acc[i][j] = (f32x4)0.f;

    for (int kk = 0; kk < EMBED; kk += 32) {
        bf16x8 a[4], b[4];
#pragma unroll
        for (int i = 0; i < 4; i++)
            a[i] = *(const bf16x8*)(xb + (size_t)(m0 + i * 16 + lr) * EMBED + kk + lk);
#pragma unroll
        for (int j = 0; j < 4; j++)
            b[j] = *(const bf16x8*)(win + (size_t)(n0 + j * 16 + lr) * EMBED + kk + lk);
#pragma unroll
        for (int i = 0; i < 4; i++)
#pragma unroll
            for (int j = 0; j < 4; j++)
                acc[i][j] = __builtin_amdgcn_mfma_f32_16x16x32_bf16(a[i], b[j], acc[i][j], 0, 0, 0);
    }

    int rowbase = (lane >> 4) * 4;
#pragma unroll
    for (int i = 0; i < 4; i++) {
#pragma unroll
        for (int j = 0; j < 4; j++) {
#pragma unroll
            for (int q = 0; q < 4; q++) {
                int m = m0 + i * 16 + rowbase + q;   // row index = b*NFRAMES + t
                int n = n0 + j * 16 + lr;            // reservoir index
                int bb = m >> 8, tt = m & 255;
                u[((size_t)tt * BATCH + bb) * RES + n] = f2bf(acc[i][j][q]);
            }
        }
    }
}

// ---------------- persistent recurrence: TWO-PHASE interleave ----------------
// 128 WGs. WG = (colblk c: 64 cols) x (pair p: row-groups g0=p, g1=p+4, 16 rows
// each). Same colblk => both phases share the SAME B fragments. Per step the WG
// runs phase g0 then g1, software-pipelined: A1 issued under g0's epilogue, and
// each group's stamp propagates during the other group's phase, so the 32-WG
// group polls are pre-satisfied -> the serial sync chain is hidden.
// State ring in u-slots (cached A-loads safe, no fences); sc0sc1 write-through
// stores; monotone stamp flags.
__global__ __launch_bounds__(512, 1) void recur_kernel(const u16* __restrict__ res,
                                                       u16* __restrict__ u,
                                                       const u16* __restrict__ s0,
                                                       unsigned* __restrict__ flags) {
    __shared__ float part[8][16][66];
    const int lane = threadIdx.x & 63;
    const int w = threadIdx.x >> 6;
    const int c = (int)(blockIdx.x & 31);        // colblk: 64 cols
    const int p = (int)(blockIdx.x >> 5);        // 0..3
    const int g0 = p, g1 = p + 4;
    const int m0a = g0 * 16, m0b = g1 * 16;
    const int n0 = c * 64;
    const int lr = lane & 15;
    const int lk = (lane >> 4) * 8;
    const int rb = (lane >> 4) * 4;
    const int kbase = w * 256;
    unsigned* myflag0 = flags + g0 * 32 + c;
    unsigned* myflag1 = flags + g1 * 32 + c;
    const unsigned* pollflag0 = flags + g0 * 32 + (lane & 31);
    const unsigned* pollflag1 = flags + g1 * 32 + (lane & 31);

    // reservoir B-fragments (shared by both phases)
    bf16x8 bfr[4][8];
#pragma unroll
    for (int jf = 0; jf < 4; jf++)
#pragma unroll
        for (int kk = 0; kk < 8; kk++) {
            const u16* bp = res + (size_t)(n0 + jf * 16 + lr) * RES + kbase + kk * 32 + lk;
            asm volatile("global_load_dwordx4 %0, %1, off"
                         : "=v"(bfr[jf][kk]) : "v"(bp));
        }
    asm volatile("s_waitcnt vmcnt(0)" ::: "memory");

    const int er = threadIdx.x >> 5;          // 0..15
    const int ec = (threadIdx.x & 31) * 2;    // 0..62
    const size_t gcol = (size_t)er * RES + n0 + ec;
    const size_t gidx0 = (size_t)m0a * RES + gcol;
    const size_t gidx1 = (size_t)m0b * RES + gcol;

    for (int t = 0; t < NFRAMES; t++) {
        const u16* sin = (t == 0) ? s0 : u + (size_t)(t - 1) * BATCH * RES;
        u16* sout = u + (size_t)t * BATCH * RES;
        const unsigned stamp = (unsigned)(t + 1);

        // ===== phase g0 =====
        if (t > 0) {
            if (w == 0) poll32(pollflag0, (unsigned)t);
            __syncthreads();
        }
        unsigned uv0 = *(const unsigned*)(sout + gidx0);

        const u16* abase0 = sin + (size_t)(m0a + lr) * RES + kbase + lk;
        bf16x8 a0[8];
#pragma unroll
        for (int kk = 0; kk < 8; kk++)
            asm volatile("global_load_dwordx4 %0, %1, off"
                         : "=v"(a0[kk]) : "v"(abase0 + kk * 32));

        f32x4 acc[4];
#pragma unroll
        for (int jf = 0; jf < 4; jf++) acc[jf] = (f32x4)0.f;
        asm volatile("s_waitcnt vmcnt(4)" ::: "memory");
        __builtin_amdgcn_sched_barrier(0);
#pragma unroll
        for (int kk = 0; kk < 4; kk++)
#pragma unroll
            for (int jf = 0; jf < 4; jf++)
                acc[jf] = __builtin_amdgcn_mfma_f32_16x16x32_bf16(a0[kk], bfr[jf][kk], acc[jf], 0, 0, 0);
        asm volatile("s_waitcnt vmcnt(0)" ::: "memory");
        __builtin_amdgcn_sched_barrier(0);
#pragma unroll
        for (int kk = 4; kk < 8; kk++)
#pragma unroll
            for (int jf = 0; jf < 4; jf++)
                acc[jf] = __builtin_amdgcn_mfma_f32_16x16x32_bf16(a0[kk], bfr[jf][kk], acc[jf], 0, 0, 0);

#pragma unroll
        for (int jf = 0; jf < 4; jf++)
#pragma unroll
            for (int q = 0; q < 4; q++)
                part[w][rb + q][jf * 16 + lr] = acc[jf][q];
        // mid-poll: wave0 checks g1's producers while others reach the barrier
        if (t > 0 && w == 0) poll32(pollflag1, (unsigned)t);
        __syncthreads();

        // issue phase-g1 A-loads now -> latency hides under g0's epilogue
        unsigned uv1 = *(const unsigned*)(sout + gidx1);
        const u16* abase1 = sin + (size_t)(m0b + lr) * RES + kbase + lk;
        bf16x8 a1[8];
#pragma unroll
        for (int kk = 0; kk < 8; kk++)
            asm volatile("global_load_dwordx4 %0, %1, off"
                         : "=v"(a1[kk]) : "v"(abase1 + kk * 32));

        // epilogue g0
        {
            float sx = 0.f, sy = 0.f;
#pragma unroll
            for (int ww = 0; ww < 8; ww++) {
                float2 v = *(const float2*)&part[ww][er][ec];
                sx += v.x; sy += v.y;
            }
            float v0 = tanh_fast(sx + bf2f((u16)(uv0 & 0xFFFF)));
            float v1 = tanh_fast(sy + bf2f((u16)(uv0 >> 16)));
            unsigned pk = (unsigned)f2bf(v0) | ((unsigned)f2bf(v1) << 16);
            asm volatile("global_store_dword %0, %1, off sc0 sc1"
                         :: "v"(sout + gidx0), "v"(pk) : "memory");
        }
        asm volatile("s_waitcnt vmcnt(0)" ::: "memory");   // a1 ready + g0 stores acked
        __builtin_amdgcn_sched_barrier(0);
        __syncthreads();
        if (t != NFRAMES - 1 && threadIdx.x == 0)
            asm volatile("global_store_dword %0, %1, off sc0 sc1"
                         :: "v"(myflag0), "v"(stamp) : "memory");

        // ===== phase g1 (A already in registers) =====
#pragma unroll
        for (int jf = 0; jf < 4; jf++) acc[jf] = (f32x4)0.f;
#pragma unroll
        for (int kk = 0; kk < 8; kk++)
#pragma unroll
            for (int jf = 0; jf < 4; jf++)
                acc[jf] = __builtin_amdgcn_mfma_f32_16x16x32_bf16(a1[kk], bfr[jf][kk], acc[jf], 0, 0, 0);

#pragma unroll
        for (int jf = 0; jf < 4; jf++)
#pragma unroll
            for (int q = 0; q < 4; q++)
                part[w][rb + q][jf * 16 + lr] = acc[jf][q];
        __syncthreads();

        {
            float sx = 0.f, sy = 0.f;
#pragma unroll
            for (int ww = 0; ww < 8; ww++) {
                float2 v = *(const float2*)&part[ww][er][ec];
                sx += v.x; sy += v.y;
            }
            float v0 = tanh_fast(sx + bf2f((u16)(uv1 & 0xFFFF)));
            float v1 = tanh_fast(sy + bf2f((u16)(uv1 >> 16)));
            unsigned pk = (unsigned)f2bf(v0) | ((unsigned)f2bf(v1) << 16);
            asm volatile("global_store_dword %0, %1, off sc0 sc1"
                         :: "v"(sout + gidx1), "v"(pk) : "memory");
        }
        asm volatile("s_waitcnt vmcnt(0)" ::: "memory");
        __syncthreads();   // also protects part[] reuse next iteration
        if (t != NFRAMES - 1 && threadIdx.x == 0)
            asm volatile("global_store_dword %0, %1, off sc0 sc1"
                         :: "v"(myflag1), "v"(stamp) : "memory");
    }
}

// ---------------- head: logits[b,c] = sum_r s[b,r]*W_out[c,r] + bias[c] ----------------
__global__ __launch_bounds__(512) void head_kernel(const u16* __restrict__ sin,
                                                   const u16* __restrict__ wout,
                                                   const float* __restrict__ bias,
                                                   float* __restrict__ out) {
    __shared__ float part[8][32][33];
    int lane = threadIdx.x & 63;
    int w = threadIdx.x >> 6;
    int m0 = blockIdx.x * 32;
    int n0 = blockIdx.y * 32;   // over padded 1024
    int k0 = w * 256;
    int lr = lane & 15;
    int lk = (lane >> 4) * 8;

    f32x4 acc[2][2];
#pragma unroll
    for (int i = 0; i < 2; i++)
#pragma unroll
        for (int j = 0; j < 2; j++) acc[i][j] = (f32x4)0.f;

    for (int kk = k0; kk < k0 + 256; kk += 32) {
        bf16x8 a[2], b[2];
#pragma unroll
        for (int i = 0; i < 2; i++)
            a[i] = *(const bf16x8*)(sin + (size_t)(m0 + i * 16 + lr) * RES + kk + lk);
#pragma unroll
        for (int j = 0; j < 2; j++) {
            int row = n0 + j * 16 + lr;
            if (row > NCLS - 1) row = NCLS - 1;  // clamp, result unused
            b[j] = *(const bf16x8*)(wout + (size_t)row * RES + kk + lk);
        }
#pragma unroll
        for (int i = 0; i < 2; i++)
#pragma unroll
            for (int j = 0; j < 2; j++)
                acc[i][j] = __builtin_amdgcn_mfma_f32_16x16x32_bf16(a[i], b[j], acc[i][j], 0, 0, 0);
    }

    int rowbase = (lane >> 4) * 4;
#pragma unroll
    for (int i = 0; i < 2; i++)
#pragma unroll
        for (int j = 0; j < 2; j++)
#pragma unroll
            for (int q = 0; q < 4; q++)
                part[w][i * 16 + rowbase + q][j * 16 + lr] = acc[i][j][q];

    __syncthreads();

    for (int idx = threadIdx.x; idx < 1024; idx += 512) {
        int r = idx >> 5, c = idx & 31;
        float s = 0.f;
#pragma unroll
        for (int ww = 0; ww < 8; ww++) s += part[ww][r][c];
        int cg = n0 + c;
        if (cg < NCLS)
            out[(size_t)(m0 + r) * NCLS + cg] = s + bias[cg];
    }
}

extern "C" void kernel_launch(void* const* d_in, const int* in_sizes, int n_in,
                              void* d_out, int out_size, void* d_ws, size_t ws_size,
                              hipStream_t stream) {
    const float* x_f    = (const float*)d_in[0];  // [128,256,768]
    const float* res_f  = (const float*)d_in[1];  // [2048,2048]
    const float* win_f  = (const float*)d_in[2];  // [2048,768]
    const float* wout_f = (const float*)d_in[3];  // [1000,2048]
    const float* bias   = (const float*)d_in[4];  // [1000]
    float* out = (float*)d_out;

    char* ws = (char*)d_ws;
    size_t off = 0;
    auto alloc = [&](size_t bytes) -> void* {
        void* p = ws + off;
        off += (bytes + 255) & ~(size_t)255;
        return p;
    };
    u16* res_b  = (u16*)alloc((size_t)RES * RES * 2);
    u16* win_b  = (u16*)alloc((size_t)RES * EMBED * 2);
    u16* wout_b = (u16*)alloc((size_t)NCLS * RES * 2);
    u16* x_b    = (u16*)alloc((size_t)BATCH * NFRAMES * EMBED * 2);
    u16* u      = (u16*)alloc((size_t)NFRAMES * BATCH * RES * 2);  // u / state ring
    u16* s0     = (u16*)alloc((size_t)BATCH * RES * 2);            // zero initial state
    unsigned* flags = (unsigned*)alloc(1024);

    // weight / input conversion to bf16
    cvt_kernel<<<dim3(1024), dim3(256), 0, stream>>>(res_f, res_b, RES * RES / 4);
    cvt_kernel<<<dim3(512), dim3(256), 0, stream>>>(win_f, win_b, RES * EMBED / 4);
    cvt_kernel<<<dim3(512), dim3(256), 0, stream>>>(wout_f, wout_b, NCLS * RES / 4);
    cvt_kernel<<<dim3(2048), dim3(256), 0, stream>>>(x_f, x_b, BATCH * NFRAMES * EMBED / 4);

    // state0 = 0, flags = 0 (ws poisoned 0xAA; re-init every call)
    hipMemsetAsync(s0, 0, (size_t)BATCH * RES * 2, stream);
    hipMemsetAsync(flags, 0, 1024, stream);

    // u[t,b,r] projection GEMM
    proj_kernel<<<dim3(256, 16), dim3(256), 0, stream>>>(x_b, win_b, u);

    // all 256 recurrence steps in one cooperative launch; state[t] -> slot u[t]
    void* args[] = { (void*)&res_b, (void*)&u, (void*)&s0, (void*)&flags };
    hipLaunchCooperativeKernel((const void*)recur_kernel, dim3(NWG), dim3(512),
                               args, 0, stream);

    // final state lives in slot u[255]
    const u16* sfin = u + (size_t)(NFRAMES - 1) * BATCH * RES;
    head_kernel<<<dim3(4, 32), dim3(512), 0, stream>>>(sfin, wout_b, bias, out);
}

// Round 17
// 1219.617 us; speedup vs baseline: 1.6408x; 1.6408x over previous
//
#include <hip/hip_runtime.h>
#include <stdint.h>
#include <stddef.h>

#define BATCH 128
#define NFRAMES 256
#define EMBED 768
#define RES 2048
#define NCLS 1000
#define NWG 256

typedef __attribute__((ext_vector_type(8))) short bf16x8;
typedef __attribute__((ext_vector_type(4))) float f32x4;
typedef unsigned short u16;

__device__ inline u16 f2bf(float f) {
    union { float f; unsigned u; } v; v.f = f;
    unsigned r = v.u + 0x7FFFu + ((v.u >> 16) & 1u);
    return (u16)(r >> 16);
}
__device__ inline float bf2f(u16 h) {
    union { unsigned u; float f; } v; v.u = ((unsigned)h) << 16;
    return v.f;
}
// tanh(x) = 1 - 2/(e^{2x}+1), via HW exp2 + rcp (saturates correctly)
__device__ inline float tanh_fast(float x) {
    float z = __builtin_amdgcn_exp2f(x * 2.885390081777927f);  // e^{2x}
    return 1.f - 2.f * __builtin_amdgcn_rcpf(z + 1.f);
}

// ---------------- fp32 -> bf16 convert, vectorized x4 ----------------
__global__ __launch_bounds__(256) void cvt_kernel(const float* __restrict__ in,
                                                  u16* __restrict__ out, int n4) {
    int i = blockIdx.x * blockDim.x + threadIdx.x;
    int stride = gridDim.x * blockDim.x;
    for (; i < n4; i += stride) {
        float4 v = ((const float4*)in)[i];
        ushort4 o;
        o.x = f2bf(v.x); o.y = f2bf(v.y); o.z = f2bf(v.z); o.w = f2bf(v.w);
        ((ushort4*)out)[i] = o;
    }
}

// ---------------- persistent recurrence with FUSED input projection ----------------
// 8 row-groups x 32 col-blocks = 256 WGs, tile 16 rows x 64 cols, 8 waves.
// Per step t, each wave accumulates BOTH GEMMs into the same acc[4]:
//   state part: K=2048 split 8x256 (A = state[t-1] from ring, B = res)
//   input part: K=768  split 8x96  (A = x[:,t,:], B = W_in)
// The 8-wave LDS reduce then yields state@res^T + x@W_in^T per element, and the
// epilogue is tanh(sum) -- u is NEVER materialized; proj_kernel is gone.
// state[t] -> ring slot t (fresh addresses => cached A-loads safe, no fences).
// Stores write-through sc0sc1; per-group stamp flags + 64-lane poll (R12-proven).
__global__ __launch_bounds__(512, 1) void recur_kernel(const u16* __restrict__ res,
                                                       const u16* __restrict__ win,
                                                       const u16* __restrict__ xb,
                                                       u16* __restrict__ ring,
                                                       const u16* __restrict__ s0,
                                                       unsigned* __restrict__ flags) {
    __shared__ float part[8][16][66];
    const int lane = threadIdx.x & 63;
    const int w = threadIdx.x >> 6;
    const int rowgrp = (int)(blockIdx.x & 7);
    const int colblk = (int)(blockIdx.x >> 3);
    const int m0 = rowgrp * 16;
    const int n0 = colblk * 64;
    const int lr = lane & 15;
    const int lk = (lane >> 4) * 8;
    const int rb = (lane >> 4) * 4;
    const int kbase = w * 256;       // state-GEMM K slice
    const int xkbase = w * 96;       // input-GEMM K slice (768/8)
    unsigned* myflag = flags + rowgrp * 32 + colblk;
    const unsigned* pollflag = flags + rowgrp * 32 + (lane & 31);

    // reservoir B-fragments (4 col-frags x 8 K-subs)
    bf16x8 bfr[4][8];
#pragma unroll
    for (int jf = 0; jf < 4; jf++)
#pragma unroll
        for (int kk = 0; kk < 8; kk++)
            bfr[jf][kk] = *(const bf16x8*)(res + (size_t)(n0 + jf * 16 + lr) * RES + kbase + kk * 32 + lk);

    // W_in B-fragments (4 col-frags x 3 K-subs of 32)
    bf16x8 wfr[4][3];
#pragma unroll
    for (int jf = 0; jf < 4; jf++)
#pragma unroll
        for (int j = 0; j < 3; j++)
            wfr[jf][j] = *(const bf16x8*)(win + (size_t)(n0 + jf * 16 + lr) * EMBED + xkbase + j * 32 + lk);

    const int er = threadIdx.x >> 5;          // 0..15
    const int ec = (threadIdx.x & 31) * 2;    // 0..62
    const size_t gidx = (size_t)(m0 + er) * RES + n0 + ec;
    // x row pointer for this lane's fragment row (row = m0+lr), per step add t*EMBED
    const u16* xrow = xb + (size_t)(m0 + lr) * NFRAMES * EMBED + xkbase + lk;

    for (int t = 0; t < NFRAMES; t++) {
        const u16* sin = (t == 0) ? s0 : ring + (size_t)(t - 1) * BATCH * RES;
        u16* sout = ring + (size_t)t * BATCH * RES;
        const u16* abase = sin + (size_t)(m0 + lr) * RES + kbase + lk;
        const u16* xp = xrow + (size_t)t * EMBED;

        // issue x loads first (3), then state A loads (8): outstanding = 11
        bf16x8 xa[3];
#pragma unroll
        for (int j = 0; j < 3; j++)
            asm volatile("global_load_dwordx4 %0, %1, off"
                         : "=v"(xa[j]) : "v"(xp + j * 32));
        bf16x8 a[8];
#pragma unroll
        for (int kk = 0; kk < 8; kk++)
            asm volatile("global_load_dwordx4 %0, %1, off"
                         : "=v"(a[kk]) : "v"(abase + kk * 32));

        f32x4 acc[4];
#pragma unroll
        for (int jf = 0; jf < 4; jf++) acc[jf] = (f32x4)0.f;

        // input projection part (xa ready at vmcnt(8))
        asm volatile("s_waitcnt vmcnt(8)" ::: "memory");
        __builtin_amdgcn_sched_barrier(0);
#pragma unroll
        for (int j = 0; j < 3; j++)
#pragma unroll
            for (int jf = 0; jf < 4; jf++)
                acc[jf] = __builtin_amdgcn_mfma_f32_16x16x32_bf16(xa[j], wfr[jf][j], acc[jf], 0, 0, 0);

        // state part, pipelined on remaining loads
        asm volatile("s_waitcnt vmcnt(4)" ::: "memory");
        __builtin_amdgcn_sched_barrier(0);
#pragma unroll
        for (int kk = 0; kk < 4; kk++)
#pragma unroll
            for (int jf = 0; jf < 4; jf++)
                acc[jf] = __builtin_amdgcn_mfma_f32_16x16x32_bf16(a[kk], bfr[jf][kk], acc[jf], 0, 0, 0);
        asm volatile("s_waitcnt vmcnt(0)" ::: "memory");
        __builtin_amdgcn_sched_barrier(0);
#pragma unroll
        for (int kk = 4; kk < 8; kk++)
#pragma unroll
            for (int jf = 0; jf < 4; jf++)
                acc[jf] = __builtin_amdgcn_mfma_f32_16x16x32_bf16(a[kk], bfr[jf][kk], acc[jf], 0, 0, 0);

        // K-partials -> LDS
#pragma unroll
        for (int jf = 0; jf < 4; jf++)
#pragma unroll
            for (int q = 0; q < 4; q++)
                part[w][rb + q][jf * 16 + lr] = acc[jf][q];
        __syncthreads();

        // reduce 8 partials (state+input already summed) + tanh + packed store
        float sx = 0.f, sy = 0.f;
#pragma unroll
        for (int ww = 0; ww < 8; ww++) {
            float2 v = *(const float2*)&part[ww][er][ec];
            sx += v.x; sy += v.y;
        }
        float v0 = tanh_fast(sx);
        float v1 = tanh_fast(sy);
        unsigned pk = (unsigned)f2bf(v0) | ((unsigned)f2bf(v1) << 16);
        asm volatile("global_store_dword %0, %1, off sc0 sc1"
                     :: "v"(sout + gidx), "v"(pk) : "memory");

        // drain own stores, then ROW-GROUP barrier: stamp + 64-lane poll (32 flags)
        asm volatile("s_waitcnt vmcnt(0)" ::: "memory");
        __syncthreads();
        if (t != NFRAMES - 1) {
            unsigned stamp = (unsigned)(t + 1);
            if (w == 0) {
                if (lane == 0)
                    asm volatile("global_store_dword %0, %1, off sc0 sc1"
                                 :: "v"(myflag), "v"(stamp) : "memory");
                unsigned f;
                do {
                    asm volatile("global_load_dword %0, %1, off sc0 sc1\n\ts_waitcnt vmcnt(0)"
                                 : "=v"(f) : "v"(pollflag) : "memory");
                    if (__all((int)(f >= stamp))) break;
                    __builtin_amdgcn_s_sleep(2);
                } while (1);
            }
            __syncthreads();
        }
    }
}

// ---------------- head: logits[b,c] = sum_r s[b,r]*W_out[c,r] + bias[c] ----------------
__global__ __launch_bounds__(512) void head_kernel(const u16* __restrict__ sin,
                                                   const u16* __restrict__ wout,
                                                   const float* __restrict__ bias,
                                                   float* __restrict__ out) {
    __shared__ float part[8][32][33];
    int lane = threadIdx.x & 63;
    int w = threadIdx.x >> 6;
    int m0 = blockIdx.x * 32;
    int n0 = blockIdx.y * 32;   // over padded 1024
    int k0 = w * 256;
    int lr = lane & 15;
    int lk = (lane >> 4) * 8;

    f32x4 acc[2][2];
#pragma unroll
    for (int i = 0; i < 2; i++)
#pragma unroll
        for (int j = 0; j < 2; j++) acc[i][j] = (f32x4)0.f;

    for (int kk = k0; kk < k0 + 256; kk += 32) {
        bf16x8 a[2], b[2];
#pragma unroll
        for (int i = 0; i < 2; i++)
            a[i] = *(const bf16x8*)(sin + (size_t)(m0 + i * 16 + lr) * RES + kk + lk);
#pragma unroll
        for (int j = 0; j < 2; j++) {
            int row = n0 + j * 16 + lr;
            if (row > NCLS - 1) row = NCLS - 1;  // clamp, result unused
            b[j] = *(const bf16x8*)(wout + (size_t)row * RES + kk + lk);
        }
#pragma unroll
        for (int i = 0; i < 2; i++)
#pragma unroll
            for (int j = 0; j < 2; j++)
                acc[i][j] = __builtin_amdgcn_mfma_f32_16x16x32_bf16(a[i], b[j], acc[i][j], 0, 0, 0);
    }

    int rowbase = (lane >> 4) * 4;
#pragma unroll
    for (int i = 0; i < 2; i++)
#pragma unroll
        for (int j = 0; j < 2; j++)
#pragma unroll
            for (int q = 0; q < 4; q++)
                part[w][i * 16 + rowbase + q][j * 16 + lr] = acc[i][j][q];

    __syncthreads();

    for (int idx = threadIdx.x; idx < 1024; idx += 512) {
        int r = idx >> 5, c = idx & 31;
        float s = 0.f;
#pragma unroll
        for (int ww = 0; ww < 8; ww++) s += part[ww][r][c];
        int cg = n0 + c;
        if (cg < NCLS)
            out[(size_t)(m0 + r) * NCLS + cg] = s + bias[cg];
    }
}

extern "C" void kernel_launch(void* const* d_in, const int* in_sizes, int n_in,
                              void* d_out, int out_size, void* d_ws, size_t ws_size,
                              hipStream_t stream) {
    const float* x_f    = (const float*)d_in[0];  // [128,256,768]
    const float* res_f  = (const float*)d_in[1];  // [2048,2048]
    const float* win_f  = (const float*)d_in[2];  // [2048,768]
    const float* wout_f = (const float*)d_in[3];  // [1000,2048]
    const float* bias   = (const float*)d_in[4];  // [1000]
    float* out = (float*)d_out;

    char* ws = (char*)d_ws;
    size_t off = 0;
    auto alloc = [&](size_t bytes) -> void* {
        void* p = ws + off;
        off += (bytes + 255) & ~(size_t)255;
        return p;
    };
    u16* res_b  = (u16*)alloc((size_t)RES * RES * 2);
    u16* win_b  = (u16*)alloc((size_t)RES * EMBED * 2);
    u16* wout_b = (u16*)alloc((size_t)NCLS * RES * 2);
    u16* x_b    = (u16*)alloc((size_t)BATCH * NFRAMES * EMBED * 2);
    u16* ring   = (u16*)alloc((size_t)NFRAMES * BATCH * RES * 2);  // state ring
    u16* s0     = (u16*)alloc((size_t)BATCH * RES * 2);            // zero initial state
    unsigned* flags = (unsigned*)alloc(1024);

    // weight / input conversion to bf16
    cvt_kernel<<<dim3(1024), dim3(256), 0, stream>>>(res_f, res_b, RES * RES / 4);
    cvt_kernel<<<dim3(512), dim3(256), 0, stream>>>(win_f, win_b, RES * EMBED / 4);
    cvt_kernel<<<dim3(512), dim3(256), 0, stream>>>(wout_f, wout_b, NCLS * RES / 4);
    cvt_kernel<<<dim3(2048), dim3(256), 0, stream>>>(x_f, x_b, BATCH * NFRAMES * EMBED / 4);

    // state0 = 0, flags = 0 (ws poisoned 0xAA; re-init every call)
    hipMemsetAsync(s0, 0, (size_t)BATCH * RES * 2, stream);
    hipMemsetAsync(flags, 0, 1024, stream);

    // all 256 recurrence steps (with fused input projection) in one launch
    void* args[] = { (void*)&res_b, (void*)&win_b, (void*)&x_b, (void*)&ring,
                     (void*)&s0, (void*)&flags };
    hipLaunchCooperativeKernel((const void*)recur_kernel, dim3(NWG), dim3(512),
                               args, 0, stream);

    // final state lives in ring slot 255
    const u16* sfin = ring + (size_t)(NFRAMES - 1) * BATCH * RES;
    head_kernel<<<dim3(4, 32), dim3(512), 0, stream>>>(sfin, wout_b, bias, out);
}